// Round 1
// baseline (1318.177 us; speedup 1.0000x reference)
//
#include <hip/hip_runtime.h>

#define NNODES 100000
#define NEDGES 1600000

// ---------------- degree / dinv ----------------
__global__ void k_init_deg(float* deg, int n) {
    int i = blockIdx.x * blockDim.x + threadIdx.x;
    if (i < n) deg[i] = 1.0f;   // self-loop contributes 1
}

__global__ void k_count_deg(const int* __restrict__ dst, float* __restrict__ deg, int e) {
    int i = blockIdx.x * blockDim.x + threadIdx.x;
    int stride = gridDim.x * blockDim.x;
    for (; i < e; i += stride) atomicAdd(&deg[dst[i]], 1.0f);
}

__global__ void k_rsqrt(float* d, int n) {
    int i = blockIdx.x * blockDim.x + threadIdx.x;
    if (i < n) d[i] = rsqrtf(d[i]);
}

// ---------------- Wcat = [Wmu | Wlv] ----------------
__global__ void k_build_wcat(const float* __restrict__ wmu, const float* __restrict__ wlv,
                             float* __restrict__ wcat) {
    int i = blockIdx.x * blockDim.x + threadIdx.x;  // 64*64
    if (i < 64 * 64) {
        int k = i >> 6, j = i & 63;
        wcat[i] = (j < 32) ? wmu[k * 32 + j] : wlv[k * 32 + (j - 32)];
    }
}

// ---------------- GEMM: U = transform(A) @ W, epilogue *dinv[row], dual-store ----------------
// transform (TRANS): a = relu(a * dinv[row] * alpha[col] + delta[col])   (fused BN+ReLU)
template <int K, bool TRANS>
__global__ __launch_bounds__(256) void k_gemm(
    const float* __restrict__ A, const float* __restrict__ W,
    const float* __restrict__ dinv, const float* __restrict__ alpha,
    const float* __restrict__ delta, float* __restrict__ U, float* __restrict__ U2, int n)
{
    constexpr int SA = 68;                 // 64 + 4 pad: bank = (4r+k)%32 -> 2-way max (free)
    __shared__ float As[64 * SA];
    __shared__ float Ws[K * 64];
    const int tid = threadIdx.x;
    const int brow = blockIdx.x * 64;
    const int tx = tid & 15, ty = tid >> 4;

    for (int i = tid; i < (K * 64) / 4; i += 256)
        reinterpret_cast<float4*>(Ws)[i] = reinterpret_cast<const float4*>(W)[i];

    float acc[4][4] = {};

    for (int kt = 0; kt < K; kt += 64) {
        __syncthreads();   // Ws visible (1st iter) / As reuse safe (later iters)
        for (int i = tid; i < 64 * 16; i += 256) {
            int r = i >> 4, c4 = i & 15;
            int grow = brow + r;
            float4 v = {0.f, 0.f, 0.f, 0.f};
            if (grow < n) {
                v = reinterpret_cast<const float4*>(A)[(size_t)grow * (K / 4) + (kt >> 2) + c4];
                if (TRANS) {
                    float dv = dinv[grow];
                    int c = kt + c4 * 4;
                    v.x = fmaxf(fmaf(v.x * dv, alpha[c + 0], delta[c + 0]), 0.f);
                    v.y = fmaxf(fmaf(v.y * dv, alpha[c + 1], delta[c + 1]), 0.f);
                    v.z = fmaxf(fmaf(v.z * dv, alpha[c + 2], delta[c + 2]), 0.f);
                    v.w = fmaxf(fmaf(v.w * dv, alpha[c + 3], delta[c + 3]), 0.f);
                }
            }
            *reinterpret_cast<float4*>(&As[r * SA + c4 * 4]) = v;
        }
        __syncthreads();
#pragma unroll 8
        for (int k = 0; k < 64; ++k) {
            float4 b = *reinterpret_cast<const float4*>(&Ws[(kt + k) * 64 + tx * 4]);
#pragma unroll
            for (int i2 = 0; i2 < 4; ++i2) {
                float a = As[(ty * 4 + i2) * SA + k];
                acc[i2][0] = fmaf(a, b.x, acc[i2][0]);
                acc[i2][1] = fmaf(a, b.y, acc[i2][1]);
                acc[i2][2] = fmaf(a, b.z, acc[i2][2]);
                acc[i2][3] = fmaf(a, b.w, acc[i2][3]);
            }
        }
    }

#pragma unroll
    for (int i2 = 0; i2 < 4; ++i2) {
        int grow = brow + ty * 4 + i2;
        if (grow < n) {
            float dv = dinv[grow];
            float4 o = {acc[i2][0] * dv, acc[i2][1] * dv, acc[i2][2] * dv, acc[i2][3] * dv};
            size_t off = (size_t)grow * 64 + tx * 4;
            *reinterpret_cast<float4*>(&U[off]) = o;    // gather source
            *reinterpret_cast<float4*>(&U2[off]) = o;   // scatter accumulator init (self-loop term)
        }
    }
}

// ---------------- edge scatter: s[dst] += u[src], lane = feature ----------------
__global__ __launch_bounds__(256) void k_scatter(
    const int* __restrict__ src, const int* __restrict__ dst,
    const float* __restrict__ u, float* __restrict__ s, int e)
{
    const int lane = threadIdx.x & 63;
    const int wave = (blockIdx.x * blockDim.x + threadIdx.x) >> 6;
    const int nw = (gridDim.x * blockDim.x) >> 6;
    for (int base = wave * 64; base < e; base += nw * 64) {
        int cnt = min(64, e - base);
        int sv = (lane < cnt) ? src[base + lane] : 0;
        int dv = (lane < cnt) ? dst[base + lane] : 0;
#pragma unroll 4
        for (int i = 0; i < cnt; ++i) {
            int se = __shfl(sv, i);
            int de = __shfl(dv, i);
            float val = u[(size_t)se * 64 + lane];
            atomicAdd(&s[(size_t)de * 64 + lane], val);
        }
    }
}

// ---------------- BN stats: sums/sumsq of y = s*dinv + b over rows ----------------
__global__ __launch_bounds__(256) void k_stats(
    const float* __restrict__ s, const float* __restrict__ dinv, const float* __restrict__ b,
    float* __restrict__ sums, float* __restrict__ sumsq, int n)
{
    __shared__ float red[2][256];
    int t = threadIdx.x;
    int c = t & 63, rg = t >> 6;   // 4 row-groups
    float bc = b[c];
    float ls = 0.f, lq = 0.f;
    for (int row = blockIdx.x * 4 + rg; row < n; row += gridDim.x * 4) {
        float y = fmaf(s[(size_t)row * 64 + c], dinv[row], bc);
        ls += y;
        lq = fmaf(y, y, lq);
    }
    red[0][t] = ls; red[1][t] = lq;
    __syncthreads();
    if (t < 64) {
        float a = red[0][t] + red[0][t + 64] + red[0][t + 128] + red[0][t + 192];
        float q = red[1][t] + red[1][t + 64] + red[1][t + 128] + red[1][t + 192];
        atomicAdd(&sums[t], a);
        atomicAdd(&sumsq[t], q);
    }
}

__global__ void k_bn_finalize(const float* __restrict__ sums, const float* __restrict__ sumsq,
                              const float* __restrict__ g, const float* __restrict__ be,
                              const float* __restrict__ b, float* __restrict__ alpha,
                              float* __restrict__ delta, int n)
{
    int c = threadIdx.x;  // 64
    float mu = sums[c] / (float)n;
    float var = sumsq[c] / (float)n - mu * mu;
    float inv = rsqrtf(var + 1e-5f);
    float a = inv * g[c];
    alpha[c] = a;
    delta[c] = fmaf(b[c] - mu, a, be[c]);
}

// ---------------- final: out = [mu ; logvar] ----------------
__global__ void k_final(const float* __restrict__ s, const float* __restrict__ dinv,
                        const float* __restrict__ bmu, const float* __restrict__ blv,
                        float* __restrict__ out, int n)
{
    int i = blockIdx.x * blockDim.x + threadIdx.x;
    int stride = gridDim.x * blockDim.x;
    int total = n * 32;
    for (; i < total; i += stride) {
        int row = i >> 5, j = i & 31;
        float dv = dinv[row];
        out[i] = fmaf(s[(size_t)row * 64 + j], dv, bmu[j]);
        out[total + i] = fmaf(s[(size_t)row * 64 + 32 + j], dv, blv[j]);
    }
}

extern "C" void kernel_launch(void* const* d_in, const int* in_sizes, int n_in,
                              void* d_out, int out_size, void* d_ws, size_t ws_size,
                              hipStream_t stream) {
    const int N = NNODES, E = NEDGES;

    const float* x   = (const float*)d_in[0];
    const int* ei    = (const int*)d_in[1];
    const float* W1  = (const float*)d_in[2];
    const float* b1  = (const float*)d_in[3];
    const float* g1  = (const float*)d_in[4];
    const float* be1 = (const float*)d_in[5];
    const float* W2  = (const float*)d_in[6];
    const float* b2  = (const float*)d_in[7];
    const float* g2  = (const float*)d_in[8];
    const float* be2 = (const float*)d_in[9];
    const float* Wmu = (const float*)d_in[10];
    const float* bmu = (const float*)d_in[11];
    const float* Wlv = (const float*)d_in[12];
    const float* blv = (const float*)d_in[13];
    float* out = (float*)d_out;

    const int* src = ei;          // edge_index[0]
    const int* dst = ei + E;      // edge_index[1]

    // workspace layout (256B aligned chunks)
    char* ws = (char*)d_ws;
    size_t off = 0;
    auto alloc = [&](size_t bytes) { char* p = ws + off; off += (bytes + 255) & ~(size_t)255; return p; };
    float* dinv  = (float*)alloc((size_t)N * 4);
    float* bufU  = (float*)alloc((size_t)N * 64 * 4);
    float* bufS  = (float*)alloc((size_t)N * 64 * 4);
    float* Wcat  = (float*)alloc(64 * 64 * 4);
    float* sums  = (float*)alloc(64 * 4);
    float* sumsq = (float*)alloc(64 * 4);
    float* alpha = (float*)alloc(64 * 4);
    float* delta = (float*)alloc(64 * 4);
    (void)ws_size;

    const int B = 256;
    dim3 blk(B);
    int gN   = (N + B - 1) / B;       // 391
    int gGemm = (N + 63) / 64;        // 1563

    // deg / dinv
    k_init_deg<<<gN, blk, 0, stream>>>(dinv, N);
    k_count_deg<<<2048, blk, 0, stream>>>(dst, dinv, E);
    k_rsqrt<<<gN, blk, 0, stream>>>(dinv, N);
    k_build_wcat<<<16, blk, 0, stream>>>(Wmu, Wlv, Wcat);

    // ---- layer 1 ----
    k_gemm<128, false><<<gGemm, blk, 0, stream>>>(x, W1, dinv, nullptr, nullptr, bufU, bufS, N);
    k_scatter<<<2048, blk, 0, stream>>>(src, dst, bufU, bufS, E);
    hipMemsetAsync(sums, 0, 512, stream);  // sums+sumsq contiguous (64*4=256 each)
    k_stats<<<256, blk, 0, stream>>>(bufS, dinv, b1, sums, sumsq, N);
    k_bn_finalize<<<1, 64, 0, stream>>>(sums, sumsq, g1, be1, b1, alpha, delta, N);

    // ---- layer 2 ----
    k_gemm<64, true><<<gGemm, blk, 0, stream>>>(bufS, W2, dinv, alpha, delta, bufU, bufS, N);
    k_scatter<<<2048, blk, 0, stream>>>(src, dst, bufU, bufS, E);
    hipMemsetAsync(sums, 0, 512, stream);
    k_stats<<<256, blk, 0, stream>>>(bufS, dinv, b2, sums, sumsq, N);
    k_bn_finalize<<<1, 64, 0, stream>>>(sums, sumsq, g2, be2, b2, alpha, delta, N);

    // ---- heads (mu ‖ logvar fused) ----
    k_gemm<64, true><<<gGemm, blk, 0, stream>>>(bufS, Wcat, dinv, alpha, delta, bufU, bufS, N);
    k_scatter<<<2048, blk, 0, stream>>>(src, dst, bufU, bufS, E);

    k_final<<<2048, blk, 0, stream>>>(bufS, dinv, bmu, blv, out, N);
}

// Round 2
// 663.521 us; speedup vs baseline: 1.9866x; 1.9866x over previous
//
#include <hip/hip_runtime.h>

#define NNODES 100000
#define NEDGES 1600000

// ---------------- int degree count (edges only; self-loop handled in aggregate) ----------------
__global__ void k_count_deg_int(const int* __restrict__ dst, int* __restrict__ deg, int e) {
    int i = blockIdx.x * blockDim.x + threadIdx.x;
    int stride = gridDim.x * blockDim.x;
    for (; i < e; i += stride) atomicAdd(&deg[dst[i]], 1);
}

__global__ void k_dinv(const int* __restrict__ deg, float* __restrict__ dinv, int n) {
    int i = blockIdx.x * blockDim.x + threadIdx.x;
    if (i < n) dinv[i] = rsqrtf((float)(deg[i] + 1));   // +1 self-loop
}

// ---------------- two-level exclusive scan over deg[N] -> rowptr[N+1] ----------------
__global__ __launch_bounds__(256) void k_block_reduce(const int* __restrict__ deg,
                                                      int* __restrict__ partials, int n) {
    __shared__ int red[256];
    int b = blockIdx.x, t = threadIdx.x;
    int base = b * 1024;
    int v = 0;
    for (int i = t; i < 1024; i += 256) {
        int idx = base + i;
        if (idx < n) v += deg[idx];
    }
    red[t] = v; __syncthreads();
    for (int s = 128; s > 0; s >>= 1) { if (t < s) red[t] += red[t + s]; __syncthreads(); }
    if (t == 0) partials[b] = red[0];
}

__global__ void k_scan_partials(int* partials, int nb) {
    if (threadIdx.x == 0 && blockIdx.x == 0) {
        int run = 0;
        for (int i = 0; i < nb; ++i) { int v = partials[i]; partials[i] = run; run += v; }
    }
}

__global__ __launch_bounds__(256) void k_block_scan(const int* __restrict__ deg,
                                                    const int* __restrict__ partials,
                                                    int* __restrict__ rowptr, int n, int etot) {
    __shared__ int red[256];
    int b = blockIdx.x, t = threadIdx.x;
    int base = b * 1024 + t * 4;
    int d[4]; int s = 0;
    for (int j = 0; j < 4; ++j) {
        int idx = base + j;
        d[j] = (idx < n) ? deg[idx] : 0;
        s += d[j];
    }
    red[t] = s; __syncthreads();
    for (int off = 1; off < 256; off <<= 1) {
        int v = (t >= off) ? red[t - off] : 0;
        __syncthreads();
        red[t] += v;
        __syncthreads();
    }
    int excl = partials[b] + (t > 0 ? red[t - 1] : 0);
    for (int j = 0; j < 4; ++j) {
        int idx = base + j;
        if (idx < n) rowptr[idx] = excl;
        excl += d[j];
    }
    if (b == 0 && t == 0) rowptr[n] = etot;
}

// ---------------- bucket fill: adj[rowptr[dst] ...] = src ----------------
__global__ void k_fill(const int* __restrict__ src, const int* __restrict__ dst,
                       int* __restrict__ cursor, int* __restrict__ adj, int e) {
    int i = blockIdx.x * blockDim.x + threadIdx.x;
    int stride = gridDim.x * blockDim.x;
    for (; i < e; i += stride) {
        int d = dst[i];
        int pos = atomicAdd(&cursor[d], 1);
        adj[pos] = src[i];
    }
}

// ---------------- Wcat = [Wmu | Wlv] ----------------
__global__ void k_build_wcat(const float* __restrict__ wmu, const float* __restrict__ wlv,
                             float* __restrict__ wcat) {
    int i = blockIdx.x * blockDim.x + threadIdx.x;  // 64*64
    if (i < 64 * 64) {
        int k = i >> 6, j = i & 63;
        wcat[i] = (j < 32) ? wmu[k * 32 + j] : wlv[k * 32 + (j - 32)];
    }
}

// ---------------- GEMM: U = transform(A) @ W, epilogue *dinv[row] ----------------
// transform (TRANS): a = relu(a * dinv[row] * alpha[col] + delta[col])   (fused BN+ReLU)
template <int K, bool TRANS>
__global__ __launch_bounds__(256) void k_gemm(
    const float* __restrict__ A, const float* __restrict__ W,
    const float* __restrict__ dinv, const float* __restrict__ alpha,
    const float* __restrict__ delta, float* __restrict__ U, int n)
{
    constexpr int SA = 68;                 // 64 + 4 pad
    __shared__ float As[64 * SA];
    __shared__ float Ws[K * 64];
    const int tid = threadIdx.x;
    const int brow = blockIdx.x * 64;
    const int tx = tid & 15, ty = tid >> 4;

    for (int i = tid; i < (K * 64) / 4; i += 256)
        reinterpret_cast<float4*>(Ws)[i] = reinterpret_cast<const float4*>(W)[i];

    float acc[4][4] = {};

    for (int kt = 0; kt < K; kt += 64) {
        __syncthreads();
        for (int i = tid; i < 64 * 16; i += 256) {
            int r = i >> 4, c4 = i & 15;
            int grow = brow + r;
            float4 v = {0.f, 0.f, 0.f, 0.f};
            if (grow < n) {
                v = reinterpret_cast<const float4*>(A)[(size_t)grow * (K / 4) + (kt >> 2) + c4];
                if (TRANS) {
                    float dv = dinv[grow];
                    int c = kt + c4 * 4;
                    v.x = fmaxf(fmaf(v.x * dv, alpha[c + 0], delta[c + 0]), 0.f);
                    v.y = fmaxf(fmaf(v.y * dv, alpha[c + 1], delta[c + 1]), 0.f);
                    v.z = fmaxf(fmaf(v.z * dv, alpha[c + 2], delta[c + 2]), 0.f);
                    v.w = fmaxf(fmaf(v.w * dv, alpha[c + 3], delta[c + 3]), 0.f);
                }
            }
            *reinterpret_cast<float4*>(&As[r * SA + c4 * 4]) = v;
        }
        __syncthreads();
#pragma unroll 8
        for (int k = 0; k < 64; ++k) {
            float4 b = *reinterpret_cast<const float4*>(&Ws[(kt + k) * 64 + tx * 4]);
#pragma unroll
            for (int i2 = 0; i2 < 4; ++i2) {
                float a = As[(ty * 4 + i2) * SA + k];
                acc[i2][0] = fmaf(a, b.x, acc[i2][0]);
                acc[i2][1] = fmaf(a, b.y, acc[i2][1]);
                acc[i2][2] = fmaf(a, b.z, acc[i2][2]);
                acc[i2][3] = fmaf(a, b.w, acc[i2][3]);
            }
        }
    }

#pragma unroll
    for (int i2 = 0; i2 < 4; ++i2) {
        int grow = brow + ty * 4 + i2;
        if (grow < n) {
            float dv = dinv[grow];
            float4 o = {acc[i2][0] * dv, acc[i2][1] * dv, acc[i2][2] * dv, acc[i2][3] * dv};
            *reinterpret_cast<float4*>(&U[(size_t)grow * 64 + tx * 4]) = o;
        }
    }
}

// ---------------- CSR aggregate: s[node] = u[node] + sum_{j in adj(node)} u[j] ----------------
__global__ __launch_bounds__(256) void k_aggregate(
    const int* __restrict__ rowptr, const int* __restrict__ adj,
    const float* __restrict__ u, float* __restrict__ s, int n)
{
    int wave = (blockIdx.x * blockDim.x + threadIdx.x) >> 6;
    int lane = threadIdx.x & 63;
    if (wave >= n) return;
    int node = wave;
    float acc = u[(size_t)node * 64 + lane];        // self-loop
    int beg = rowptr[node], end = rowptr[node + 1];
    for (int cbeg = beg; cbeg < end; cbeg += 64) {
        int cnt = min(64, end - cbeg);
        int a = (lane < cnt) ? adj[cbeg + lane] : 0;
        for (int i = 0; i < cnt; ++i) {
            int sidx = __shfl(a, i);
            acc += u[(size_t)sidx * 64 + lane];
        }
    }
    s[(size_t)node * 64 + lane] = acc;
}

// ---------------- CSR aggregate + final epilogue: out = [mu ; logvar] ----------------
__global__ __launch_bounds__(256) void k_aggregate_final(
    const int* __restrict__ rowptr, const int* __restrict__ adj,
    const float* __restrict__ u, const float* __restrict__ dinv,
    const float* __restrict__ bmu, const float* __restrict__ blv,
    float* __restrict__ out, int n)
{
    int wave = (blockIdx.x * blockDim.x + threadIdx.x) >> 6;
    int lane = threadIdx.x & 63;
    if (wave >= n) return;
    int node = wave;
    float acc = u[(size_t)node * 64 + lane];
    int beg = rowptr[node], end = rowptr[node + 1];
    for (int cbeg = beg; cbeg < end; cbeg += 64) {
        int cnt = min(64, end - cbeg);
        int a = (lane < cnt) ? adj[cbeg + lane] : 0;
        for (int i = 0; i < cnt; ++i) {
            int sidx = __shfl(a, i);
            acc += u[(size_t)sidx * 64 + lane];
        }
    }
    float dv = dinv[node];
    int total = n * 32;
    if (lane < 32)
        out[(size_t)node * 32 + lane] = fmaf(acc, dv, bmu[lane]);
    else
        out[(size_t)total + (size_t)node * 32 + (lane - 32)] = fmaf(acc, dv, blv[lane - 32]);
}

// ---------------- BN stats: sums/sumsq of y = s*dinv + b over rows ----------------
__global__ __launch_bounds__(256) void k_stats(
    const float* __restrict__ s, const float* __restrict__ dinv, const float* __restrict__ b,
    float* __restrict__ sums, float* __restrict__ sumsq, int n)
{
    __shared__ float red[2][256];
    int t = threadIdx.x;
    int c = t & 63, rg = t >> 6;   // 4 row-groups
    float bc = b[c];
    float ls = 0.f, lq = 0.f;
    for (int row = blockIdx.x * 4 + rg; row < n; row += gridDim.x * 4) {
        float y = fmaf(s[(size_t)row * 64 + c], dinv[row], bc);
        ls += y;
        lq = fmaf(y, y, lq);
    }
    red[0][t] = ls; red[1][t] = lq;
    __syncthreads();
    if (t < 64) {
        float a = red[0][t] + red[0][t + 64] + red[0][t + 128] + red[0][t + 192];
        float q = red[1][t] + red[1][t + 64] + red[1][t + 128] + red[1][t + 192];
        atomicAdd(&sums[t], a);
        atomicAdd(&sumsq[t], q);
    }
}

__global__ void k_bn_finalize(const float* __restrict__ sums, const float* __restrict__ sumsq,
                              const float* __restrict__ g, const float* __restrict__ be,
                              const float* __restrict__ b, float* __restrict__ alpha,
                              float* __restrict__ delta, int n)
{
    int c = threadIdx.x;  // 64
    float mu = sums[c] / (float)n;
    float var = sumsq[c] / (float)n - mu * mu;
    float inv = rsqrtf(var + 1e-5f);
    float a = inv * g[c];
    alpha[c] = a;
    delta[c] = fmaf(b[c] - mu, a, be[c]);
}

extern "C" void kernel_launch(void* const* d_in, const int* in_sizes, int n_in,
                              void* d_out, int out_size, void* d_ws, size_t ws_size,
                              hipStream_t stream) {
    const int N = NNODES, E = NEDGES;

    const float* x   = (const float*)d_in[0];
    const int* ei    = (const int*)d_in[1];
    const float* W1  = (const float*)d_in[2];
    const float* b1  = (const float*)d_in[3];
    const float* g1  = (const float*)d_in[4];
    const float* be1 = (const float*)d_in[5];
    const float* W2  = (const float*)d_in[6];
    const float* b2  = (const float*)d_in[7];
    const float* g2  = (const float*)d_in[8];
    const float* be2 = (const float*)d_in[9];
    const float* Wmu = (const float*)d_in[10];
    const float* bmu = (const float*)d_in[11];
    const float* Wlv = (const float*)d_in[12];
    const float* blv = (const float*)d_in[13];
    float* out = (float*)d_out;

    const int* src = ei;          // edge_index[0]
    const int* dst = ei + E;      // edge_index[1]

    // workspace layout (256B aligned chunks)
    char* ws = (char*)d_ws;
    size_t off = 0;
    auto alloc = [&](size_t bytes) { char* p = ws + off; off += (bytes + 255) & ~(size_t)255; return p; };
    float* dinv   = (float*)alloc((size_t)N * 4);
    float* bufU   = (float*)alloc((size_t)N * 64 * 4);
    float* bufS   = (float*)alloc((size_t)N * 64 * 4);
    int*   degi   = (int*)alloc((size_t)N * 4);
    int*   rowptr = (int*)alloc((size_t)(N + 1) * 4);
    int*   cursor = (int*)alloc((size_t)N * 4);
    int*   adj    = (int*)alloc((size_t)E * 4);
    int*   partials = (int*)alloc(128 * 4);
    float* Wcat   = (float*)alloc(64 * 64 * 4);
    float* sums   = (float*)alloc(64 * 4);
    float* sumsq  = (float*)alloc(64 * 4);
    float* alpha  = (float*)alloc(64 * 4);
    float* delta  = (float*)alloc(64 * 4);
    (void)ws_size;

    const int B = 256;
    dim3 blk(B);
    int gN     = (N + B - 1) / B;        // 391
    int gGemm  = (N + 63) / 64;          // 1563
    int gScan  = (N + 1023) / 1024;      // 98
    int gAgg   = (N + 3) / 4;            // 25000 (4 waves/block, 1 node/wave)

    // ---- build CSR (counting sort by dst) + dinv ----
    hipMemsetAsync(degi, 0, (size_t)N * 4, stream);
    k_count_deg_int<<<2048, blk, 0, stream>>>(dst, degi, E);
    k_dinv<<<gN, blk, 0, stream>>>(degi, dinv, N);
    k_block_reduce<<<gScan, blk, 0, stream>>>(degi, partials, N);
    k_scan_partials<<<1, 64, 0, stream>>>(partials, gScan);
    k_block_scan<<<gScan, blk, 0, stream>>>(degi, partials, rowptr, N, E);
    hipMemcpyAsync(cursor, rowptr, (size_t)N * 4, hipMemcpyDeviceToDevice, stream);
    k_fill<<<2048, blk, 0, stream>>>(src, dst, cursor, adj, E);
    k_build_wcat<<<16, blk, 0, stream>>>(Wmu, Wlv, Wcat);

    // ---- layer 1 ----
    k_gemm<128, false><<<gGemm, blk, 0, stream>>>(x, W1, dinv, nullptr, nullptr, bufU, N);
    k_aggregate<<<gAgg, blk, 0, stream>>>(rowptr, adj, bufU, bufS, N);
    hipMemsetAsync(sums, 0, 512, stream);  // sums+sumsq contiguous (64*4=256 each)
    k_stats<<<256, blk, 0, stream>>>(bufS, dinv, b1, sums, sumsq, N);
    k_bn_finalize<<<1, 64, 0, stream>>>(sums, sumsq, g1, be1, b1, alpha, delta, N);

    // ---- layer 2 ----
    k_gemm<64, true><<<gGemm, blk, 0, stream>>>(bufS, W2, dinv, alpha, delta, bufU, N);
    k_aggregate<<<gAgg, blk, 0, stream>>>(rowptr, adj, bufU, bufS, N);
    hipMemsetAsync(sums, 0, 512, stream);
    k_stats<<<256, blk, 0, stream>>>(bufS, dinv, b2, sums, sumsq, N);
    k_bn_finalize<<<1, 64, 0, stream>>>(sums, sumsq, g2, be2, b2, alpha, delta, N);

    // ---- heads (mu ‖ logvar fused) + final epilogue ----
    k_gemm<64, true><<<gGemm, blk, 0, stream>>>(bufS, Wcat, dinv, alpha, delta, bufU, N);
    k_aggregate_final<<<gAgg, blk, 0, stream>>>(rowptr, adj, bufU, dinv, bmu, blv, out, N);
}

// Round 3
// 508.147 us; speedup vs baseline: 2.5941x; 1.3058x over previous
//
#include <hip/hip_runtime.h>

#define NNODES 100000
#define NEDGES 1600000
#define KBUCK 196          // ceil(N / 512)
#define RNG 512            // nodes per bucket (dst >> 9)
#define BCAP 9216          // bucket capacity: mean 8192, sd ~90 -> 11 sigma headroom
#define CHUNK 4096         // edges per workgroup in binning pass

// ---- bf16 helpers (RNE) ----
__device__ inline unsigned short f2bf(float f) {
    union { float f; unsigned u; } a; a.f = f;
    unsigned r = (a.u + 0x7FFFu + ((a.u >> 16) & 1u)) >> 16;
    return (unsigned short)r;
}
__device__ inline float bf2f(unsigned short h) {
    union { unsigned u; float f; } a; a.u = ((unsigned)h) << 16;
    return a.f;
}

// ---------------- pass A: bin edges by dst>>9 into KBUCK buckets (LDS-staged) ----------------
// entry = (dstLocal << 17) | src   (src < 2^17, dstLocal < 2^9)
__global__ __launch_bounds__(256) void k_bin(
    const int* __restrict__ src, const int* __restrict__ dst,
    unsigned int* __restrict__ gbuf, int* __restrict__ gcount, int e)
{
    __shared__ unsigned int bins[KBUCK][64];
    __shared__ int bcount[KBUCK];
    const int tid = threadIdx.x;
    for (int i = tid; i < KBUCK; i += 256) bcount[i] = 0;
    __syncthreads();

    int base = blockIdx.x * CHUNK;
    int lim = min(e, base + CHUNK);
    for (int i = base + tid; i < lim; i += 256) {
        int d = dst[i];
        int s = src[i];
        int b = d >> 9;
        unsigned int entry = ((unsigned int)(d & 511) << 17) | (unsigned int)s;
        int idx = atomicAdd(&bcount[b], 1);
        if (idx < 64) {
            bins[b][idx] = entry;
        } else {
            int gpos = atomicAdd(&gcount[b], 1);
            if (gpos < BCAP) gbuf[(size_t)b * BCAP + gpos] = entry;
        }
    }
    __syncthreads();

    // flush: thread t owns bucket t
    for (int b = tid; b < KBUCK; b += 256) {
        int n = min(bcount[b], 64);
        if (n > 0) {
            int pos = atomicAdd(&gcount[b], n);
            int m = min(n, BCAP - pos);
            for (int i = 0; i < m; ++i)
                gbuf[(size_t)b * BCAP + pos + i] = bins[b][i];
        }
    }
}

// ---------------- pass B: per-bucket degree histogram -> deg + dinv ----------------
__global__ __launch_bounds__(256) void k_hist_dinv(
    const unsigned int* __restrict__ gbuf, const int* __restrict__ gcount,
    int* __restrict__ deg, float* __restrict__ dinv, int n)
{
    __shared__ int hist[RNG];
    const int b = blockIdx.x, tid = threadIdx.x;
    for (int i = tid; i < RNG; i += 256) hist[i] = 0;
    __syncthreads();
    int cnt = gcount[b];
    const unsigned int* buf = gbuf + (size_t)b * BCAP;
    for (int j = tid; j < cnt; j += 256)
        atomicAdd(&hist[buf[j] >> 17], 1);
    __syncthreads();
    int nbase = b * RNG;
    for (int i = tid; i < RNG; i += 256) {
        int node = nbase + i;
        if (node < n) {
            int dgi = hist[i];
            deg[node] = dgi;
            dinv[node] = rsqrtf((float)(dgi + 1));   // +1 self-loop
        }
    }
}

// ---------------- two-level exclusive scan over deg[N] -> rowptr[N+1] ----------------
__global__ __launch_bounds__(256) void k_block_reduce(const int* __restrict__ deg,
                                                      int* __restrict__ partials, int n) {
    __shared__ int red[256];
    int b = blockIdx.x, t = threadIdx.x;
    int base = b * 1024;
    int v = 0;
    for (int i = t; i < 1024; i += 256) {
        int idx = base + i;
        if (idx < n) v += deg[idx];
    }
    red[t] = v; __syncthreads();
    for (int s = 128; s > 0; s >>= 1) { if (t < s) red[t] += red[t + s]; __syncthreads(); }
    if (t == 0) partials[b] = red[0];
}

__global__ void k_scan_partials(int* partials, int nb) {
    if (threadIdx.x == 0 && blockIdx.x == 0) {
        int run = 0;
        for (int i = 0; i < nb; ++i) { int v = partials[i]; partials[i] = run; run += v; }
    }
}

__global__ __launch_bounds__(256) void k_block_scan(const int* __restrict__ deg,
                                                    const int* __restrict__ partials,
                                                    int* __restrict__ rowptr, int n, int etot) {
    __shared__ int red[256];
    int b = blockIdx.x, t = threadIdx.x;
    int base = b * 1024 + t * 4;
    int d[4]; int s = 0;
    for (int j = 0; j < 4; ++j) {
        int idx = base + j;
        d[j] = (idx < n) ? deg[idx] : 0;
        s += d[j];
    }
    red[t] = s; __syncthreads();
    for (int off = 1; off < 256; off <<= 1) {
        int v = (t >= off) ? red[t - off] : 0;
        __syncthreads();
        red[t] += v;
        __syncthreads();
    }
    int excl = partials[b] + (t > 0 ? red[t - 1] : 0);
    for (int j = 0; j < 4; ++j) {
        int idx = base + j;
        if (idx < n) rowptr[idx] = excl;
        excl += d[j];
    }
    if (b == 0 && t == 0) rowptr[n] = etot;
}

// ---------------- pass C: per-bucket scatter into adj (XCD-local writes) ----------------
__global__ __launch_bounds__(256) void k_fill_local(
    const unsigned int* __restrict__ gbuf, const int* __restrict__ gcount,
    const int* __restrict__ rowptr, int* __restrict__ adj, int n)
{
    __shared__ int cursor[RNG];
    const int b = blockIdx.x, tid = threadIdx.x;
    int nbase = b * RNG;
    for (int i = tid; i < RNG; i += 256) {
        int node = nbase + i;
        cursor[i] = (node < n) ? rowptr[node] : 0;
    }
    __syncthreads();
    int cnt = gcount[b];
    const unsigned int* buf = gbuf + (size_t)b * BCAP;
    for (int j = tid; j < cnt; j += 256) {
        unsigned int e = buf[j];
        int dl = e >> 17;
        int s = (int)(e & 0x1FFFFu);
        int pos = atomicAdd(&cursor[dl], 1);
        adj[pos] = s;
    }
}

// ---------------- Wcat = [Wmu | Wlv] ----------------
__global__ void k_build_wcat(const float* __restrict__ wmu, const float* __restrict__ wlv,
                             float* __restrict__ wcat) {
    int i = blockIdx.x * blockDim.x + threadIdx.x;  // 64*64
    if (i < 64 * 64) {
        int k = i >> 6, j = i & 63;
        wcat[i] = (j < 32) ? wmu[k * 32 + j] : wlv[k * 32 + (j - 32)];
    }
}

// ---------------- GEMM: U(bf16) = transform(A) @ W * dinv[row] ----------------
template <int K, bool TRANS>
__global__ __launch_bounds__(256) void k_gemm(
    const float* __restrict__ A, const float* __restrict__ W,
    const float* __restrict__ dinv, const float* __restrict__ alpha,
    const float* __restrict__ delta, unsigned short* __restrict__ U, int n)
{
    constexpr int SA = 68;                 // 64 + 4 pad
    __shared__ float As[64 * SA];
    __shared__ float Ws[K * 64];
    const int tid = threadIdx.x;
    const int brow = blockIdx.x * 64;
    const int tx = tid & 15, ty = tid >> 4;

    for (int i = tid; i < (K * 64) / 4; i += 256)
        reinterpret_cast<float4*>(Ws)[i] = reinterpret_cast<const float4*>(W)[i];

    float acc[4][4] = {};

    for (int kt = 0; kt < K; kt += 64) {
        __syncthreads();
        for (int i = tid; i < 64 * 16; i += 256) {
            int r = i >> 4, c4 = i & 15;
            int grow = brow + r;
            float4 v = {0.f, 0.f, 0.f, 0.f};
            if (grow < n) {
                v = reinterpret_cast<const float4*>(A)[(size_t)grow * (K / 4) + (kt >> 2) + c4];
                if (TRANS) {
                    float dv = dinv[grow];
                    int c = kt + c4 * 4;
                    v.x = fmaxf(fmaf(v.x * dv, alpha[c + 0], delta[c + 0]), 0.f);
                    v.y = fmaxf(fmaf(v.y * dv, alpha[c + 1], delta[c + 1]), 0.f);
                    v.z = fmaxf(fmaf(v.z * dv, alpha[c + 2], delta[c + 2]), 0.f);
                    v.w = fmaxf(fmaf(v.w * dv, alpha[c + 3], delta[c + 3]), 0.f);
                }
            }
            *reinterpret_cast<float4*>(&As[r * SA + c4 * 4]) = v;
        }
        __syncthreads();
#pragma unroll 8
        for (int k = 0; k < 64; ++k) {
            float4 b = *reinterpret_cast<const float4*>(&Ws[(kt + k) * 64 + tx * 4]);
#pragma unroll
            for (int i2 = 0; i2 < 4; ++i2) {
                float a = As[(ty * 4 + i2) * SA + k];
                acc[i2][0] = fmaf(a, b.x, acc[i2][0]);
                acc[i2][1] = fmaf(a, b.y, acc[i2][1]);
                acc[i2][2] = fmaf(a, b.z, acc[i2][2]);
                acc[i2][3] = fmaf(a, b.w, acc[i2][3]);
            }
        }
    }

#pragma unroll
    for (int i2 = 0; i2 < 4; ++i2) {
        int grow = brow + ty * 4 + i2;
        if (grow < n) {
            float dv = dinv[grow];
            ushort4 o;
            o.x = f2bf(acc[i2][0] * dv);
            o.y = f2bf(acc[i2][1] * dv);
            o.z = f2bf(acc[i2][2] * dv);
            o.w = f2bf(acc[i2][3] * dv);
            *reinterpret_cast<ushort4*>(&U[(size_t)grow * 64 + tx * 4]) = o;
        }
    }
}

// ---------------- CSR aggregate: s[node] = u[node] + sum_{j in adj(node)} u[j] ----------------
__global__ __launch_bounds__(256) void k_aggregate(
    const int* __restrict__ rowptr, const int* __restrict__ adj,
    const unsigned short* __restrict__ u, float* __restrict__ s, int n)
{
    int wave = (blockIdx.x * blockDim.x + threadIdx.x) >> 6;
    int lane = threadIdx.x & 63;
    if (wave >= n) return;
    int node = wave;
    float acc = bf2f(u[(size_t)node * 64 + lane]);        // self-loop
    int beg = rowptr[node], end = rowptr[node + 1];
    for (int cbeg = beg; cbeg < end; cbeg += 64) {
        int cnt = min(64, end - cbeg);
        int a = (lane < cnt) ? adj[cbeg + lane] : 0;
        for (int i = 0; i < cnt; ++i) {
            int sidx = __shfl(a, i);
            acc += bf2f(u[(size_t)sidx * 64 + lane]);
        }
    }
    s[(size_t)node * 64 + lane] = acc;
}

// ---------------- CSR aggregate + final epilogue: out = [mu ; logvar] ----------------
__global__ __launch_bounds__(256) void k_aggregate_final(
    const int* __restrict__ rowptr, const int* __restrict__ adj,
    const unsigned short* __restrict__ u, const float* __restrict__ dinv,
    const float* __restrict__ bmu, const float* __restrict__ blv,
    float* __restrict__ out, int n)
{
    int wave = (blockIdx.x * blockDim.x + threadIdx.x) >> 6;
    int lane = threadIdx.x & 63;
    if (wave >= n) return;
    int node = wave;
    float acc = bf2f(u[(size_t)node * 64 + lane]);
    int beg = rowptr[node], end = rowptr[node + 1];
    for (int cbeg = beg; cbeg < end; cbeg += 64) {
        int cnt = min(64, end - cbeg);
        int a = (lane < cnt) ? adj[cbeg + lane] : 0;
        for (int i = 0; i < cnt; ++i) {
            int sidx = __shfl(a, i);
            acc += bf2f(u[(size_t)sidx * 64 + lane]);
        }
    }
    float dv = dinv[node];
    int total = n * 32;
    if (lane < 32)
        out[(size_t)node * 32 + lane] = fmaf(acc, dv, bmu[lane]);
    else
        out[(size_t)total + (size_t)node * 32 + (lane - 32)] = fmaf(acc, dv, blv[lane - 32]);
}

// ---------------- BN stats: sums/sumsq of y = s*dinv + b over rows ----------------
__global__ __launch_bounds__(256) void k_stats(
    const float* __restrict__ s, const float* __restrict__ dinv, const float* __restrict__ b,
    float* __restrict__ sums, float* __restrict__ sumsq, int n)
{
    __shared__ float red[2][256];
    int t = threadIdx.x;
    int c = t & 63, rg = t >> 6;   // 4 row-groups
    float bc = b[c];
    float ls = 0.f, lq = 0.f;
    for (int row = blockIdx.x * 4 + rg; row < n; row += gridDim.x * 4) {
        float y = fmaf(s[(size_t)row * 64 + c], dinv[row], bc);
        ls += y;
        lq = fmaf(y, y, lq);
    }
    red[0][t] = ls; red[1][t] = lq;
    __syncthreads();
    if (t < 64) {
        float a = red[0][t] + red[0][t + 64] + red[0][t + 128] + red[0][t + 192];
        float q = red[1][t] + red[1][t + 64] + red[1][t + 128] + red[1][t + 192];
        atomicAdd(&sums[t], a);
        atomicAdd(&sumsq[t], q);
    }
}

__global__ void k_bn_finalize(const float* __restrict__ sums, const float* __restrict__ sumsq,
                              const float* __restrict__ g, const float* __restrict__ be,
                              const float* __restrict__ b, float* __restrict__ alpha,
                              float* __restrict__ delta, int n)
{
    int c = threadIdx.x;  // 64
    float mu = sums[c] / (float)n;
    float var = sumsq[c] / (float)n - mu * mu;
    float inv = rsqrtf(var + 1e-5f);
    float a = inv * g[c];
    alpha[c] = a;
    delta[c] = fmaf(b[c] - mu, a, be[c]);
}

extern "C" void kernel_launch(void* const* d_in, const int* in_sizes, int n_in,
                              void* d_out, int out_size, void* d_ws, size_t ws_size,
                              hipStream_t stream) {
    const int N = NNODES, E = NEDGES;

    const float* x   = (const float*)d_in[0];
    const int* ei    = (const int*)d_in[1];
    const float* W1  = (const float*)d_in[2];
    const float* b1  = (const float*)d_in[3];
    const float* g1  = (const float*)d_in[4];
    const float* be1 = (const float*)d_in[5];
    const float* W2  = (const float*)d_in[6];
    const float* b2  = (const float*)d_in[7];
    const float* g2  = (const float*)d_in[8];
    const float* be2 = (const float*)d_in[9];
    const float* Wmu = (const float*)d_in[10];
    const float* bmu = (const float*)d_in[11];
    const float* Wlv = (const float*)d_in[12];
    const float* blv = (const float*)d_in[13];
    float* out = (float*)d_out;

    const int* src = ei;          // edge_index[0]
    const int* dst = ei + E;      // edge_index[1]

    // workspace layout (256B aligned chunks)
    char* ws = (char*)d_ws;
    size_t off = 0;
    auto alloc = [&](size_t bytes) { char* p = ws + off; off += (bytes + 255) & ~(size_t)255; return p; };
    float*          dinv   = (float*)alloc((size_t)N * 4);
    unsigned short* bufU   = (unsigned short*)alloc((size_t)N * 64 * 2);
    float*          bufS   = (float*)alloc((size_t)N * 64 * 4);
    int*            degi   = (int*)alloc((size_t)N * 4);
    int*            rowptr = (int*)alloc((size_t)(N + 1) * 4);
    int*            adj    = (int*)alloc((size_t)E * 4);
    unsigned int*   gbuf   = (unsigned int*)alloc((size_t)KBUCK * BCAP * 4);
    int*            gcount = (int*)alloc((size_t)KBUCK * 4);
    int*            partials = (int*)alloc(128 * 4);
    float*          Wcat   = (float*)alloc(64 * 64 * 4);
    float*          sums   = (float*)alloc(64 * 4);
    float*          sumsq  = (float*)alloc(64 * 4);
    float*          alpha  = (float*)alloc(64 * 4);
    float*          delta  = (float*)alloc(64 * 4);
    (void)ws_size;

    const int B = 256;
    dim3 blk(B);
    int gGemm  = (N + 63) / 64;          // 1563
    int gScan  = (N + 1023) / 1024;      // 98
    int gAgg   = (N + 3) / 4;            // 25000 (4 waves/block, 1 node/wave)
    int gBin   = (E + CHUNK - 1) / CHUNK; // 391

    // ---- build CSR: bin -> hist/dinv -> scan -> local fill ----
    hipMemsetAsync(gcount, 0, (size_t)KBUCK * 4, stream);
    k_bin<<<gBin, blk, 0, stream>>>(src, dst, gbuf, gcount, E);
    k_hist_dinv<<<KBUCK, blk, 0, stream>>>(gbuf, gcount, degi, dinv, N);
    k_block_reduce<<<gScan, blk, 0, stream>>>(degi, partials, N);
    k_scan_partials<<<1, 64, 0, stream>>>(partials, gScan);
    k_block_scan<<<gScan, blk, 0, stream>>>(degi, partials, rowptr, N, E);
    k_fill_local<<<KBUCK, blk, 0, stream>>>(gbuf, gcount, rowptr, adj, N);
    k_build_wcat<<<16, blk, 0, stream>>>(Wmu, Wlv, Wcat);

    // ---- layer 1 ----
    k_gemm<128, false><<<gGemm, blk, 0, stream>>>(x, W1, dinv, nullptr, nullptr, bufU, N);
    k_aggregate<<<gAgg, blk, 0, stream>>>(rowptr, adj, bufU, bufS, N);
    hipMemsetAsync(sums, 0, 512, stream);  // sums+sumsq contiguous (64*4=256 each)
    k_stats<<<256, blk, 0, stream>>>(bufS, dinv, b1, sums, sumsq, N);
    k_bn_finalize<<<1, 64, 0, stream>>>(sums, sumsq, g1, be1, b1, alpha, delta, N);

    // ---- layer 2 ----
    k_gemm<64, true><<<gGemm, blk, 0, stream>>>(bufS, W2, dinv, alpha, delta, bufU, N);
    k_aggregate<<<gAgg, blk, 0, stream>>>(rowptr, adj, bufU, bufS, N);
    hipMemsetAsync(sums, 0, 512, stream);
    k_stats<<<256, blk, 0, stream>>>(bufS, dinv, b2, sums, sumsq, N);
    k_bn_finalize<<<1, 64, 0, stream>>>(sums, sumsq, g2, be2, b2, alpha, delta, N);

    // ---- heads (mu ‖ logvar fused) + final epilogue ----
    k_gemm<64, true><<<gGemm, blk, 0, stream>>>(bufS, Wcat, dinv, alpha, delta, bufU, N);
    k_aggregate_final<<<gAgg, blk, 0, stream>>>(rowptr, adj, bufU, dinv, bmu, blv, out, N);
}

// Round 4
// 366.343 us; speedup vs baseline: 3.5982x; 1.3871x over previous
//
#include <hip/hip_runtime.h>

#define NNODES 100000
#define NEDGES 1600000
#define KBUCK 196          // ceil(N / 512)
#define RNG 512            // nodes per bucket (dst >> 9)
#define BCAP 9216          // bucket capacity: mean 8192, sd ~90 -> 11 sigma headroom
#define CHUNK 4096         // edges per workgroup in binning pass

// ---- bf16 helpers (RNE) ----
__device__ inline unsigned short f2bf(float f) {
    union { float f; unsigned u; } a; a.f = f;
    unsigned r = (a.u + 0x7FFFu + ((a.u >> 16) & 1u)) >> 16;
    return (unsigned short)r;
}
__device__ inline float bf2f(unsigned short h) {
    union { unsigned u; float f; } a; a.u = ((unsigned)h) << 16;
    return a.f;
}

// ---------------- pass A: bin edges by dst>>9 into KBUCK buckets (LDS-staged) ----------------
// entry = (dstLocal << 17) | src   (src < 2^17, dstLocal < 2^9)
__global__ __launch_bounds__(256) void k_bin(
    const int* __restrict__ src, const int* __restrict__ dst,
    unsigned int* __restrict__ gbuf, int* __restrict__ gcount, int e)
{
    __shared__ unsigned int bins[KBUCK][64];
    __shared__ int bcount[KBUCK];
    const int tid = threadIdx.x;
    for (int i = tid; i < KBUCK; i += 256) bcount[i] = 0;
    __syncthreads();

    int base = blockIdx.x * CHUNK;
    int lim = min(e, base + CHUNK);
    for (int i = base + tid; i < lim; i += 256) {
        int d = dst[i];
        int s = src[i];
        int b = d >> 9;
        unsigned int entry = ((unsigned int)(d & 511) << 17) | (unsigned int)s;
        int idx = atomicAdd(&bcount[b], 1);
        if (idx < 64) {
            bins[b][idx] = entry;
        } else {
            int gpos = atomicAdd(&gcount[b], 1);
            if (gpos < BCAP) gbuf[(size_t)b * BCAP + gpos] = entry;
        }
    }
    __syncthreads();

    // flush: thread t owns bucket t
    for (int b = tid; b < KBUCK; b += 256) {
        int n = min(bcount[b], 64);
        if (n > 0) {
            int pos = atomicAdd(&gcount[b], n);
            int m = min(n, BCAP - pos);
            for (int i = 0; i < m; ++i)
                gbuf[(size_t)b * BCAP + pos + i] = bins[b][i];
        }
    }
}

// ---------------- pass B: per-bucket degree histogram -> deg + dinv ----------------
__global__ __launch_bounds__(256) void k_hist_dinv(
    const unsigned int* __restrict__ gbuf, const int* __restrict__ gcount,
    int* __restrict__ deg, float* __restrict__ dinv, int n)
{
    __shared__ int hist[RNG];
    const int b = blockIdx.x, tid = threadIdx.x;
    for (int i = tid; i < RNG; i += 256) hist[i] = 0;
    __syncthreads();
    int cnt = gcount[b];
    const unsigned int* buf = gbuf + (size_t)b * BCAP;
    for (int j = tid; j < cnt; j += 256)
        atomicAdd(&hist[buf[j] >> 17], 1);
    __syncthreads();
    int nbase = b * RNG;
    for (int i = tid; i < RNG; i += 256) {
        int node = nbase + i;
        if (node < n) {
            int dgi = hist[i];
            deg[node] = dgi;
            dinv[node] = rsqrtf((float)(dgi + 1));   // +1 self-loop
        }
    }
}

// ---------------- two-level exclusive scan over deg[N] -> rowptr[N+1] ----------------
__global__ __launch_bounds__(256) void k_block_reduce(const int* __restrict__ deg,
                                                      int* __restrict__ partials, int n) {
    __shared__ int red[256];
    int b = blockIdx.x, t = threadIdx.x;
    int base = b * 1024;
    int v = 0;
    for (int i = t; i < 1024; i += 256) {
        int idx = base + i;
        if (idx < n) v += deg[idx];
    }
    red[t] = v; __syncthreads();
    for (int s = 128; s > 0; s >>= 1) { if (t < s) red[t] += red[t + s]; __syncthreads(); }
    if (t == 0) partials[b] = red[0];
}

__global__ void k_scan_partials(int* partials, int nb) {
    if (threadIdx.x == 0 && blockIdx.x == 0) {
        int run = 0;
        for (int i = 0; i < nb; ++i) { int v = partials[i]; partials[i] = run; run += v; }
    }
}

__global__ __launch_bounds__(256) void k_block_scan(const int* __restrict__ deg,
                                                    const int* __restrict__ partials,
                                                    int* __restrict__ rowptr, int n, int etot) {
    __shared__ int red[256];
    int b = blockIdx.x, t = threadIdx.x;
    int base = b * 1024 + t * 4;
    int d[4]; int s = 0;
    for (int j = 0; j < 4; ++j) {
        int idx = base + j;
        d[j] = (idx < n) ? deg[idx] : 0;
        s += d[j];
    }
    red[t] = s; __syncthreads();
    for (int off = 1; off < 256; off <<= 1) {
        int v = (t >= off) ? red[t - off] : 0;
        __syncthreads();
        red[t] += v;
        __syncthreads();
    }
    int excl = partials[b] + (t > 0 ? red[t - 1] : 0);
    for (int j = 0; j < 4; ++j) {
        int idx = base + j;
        if (idx < n) rowptr[idx] = excl;
        excl += d[j];
    }
    if (b == 0 && t == 0) rowptr[n] = etot;
}

// ---------------- pass C: per-bucket scatter into adj (XCD-local writes) ----------------
__global__ __launch_bounds__(256) void k_fill_local(
    const unsigned int* __restrict__ gbuf, const int* __restrict__ gcount,
    const int* __restrict__ rowptr, int* __restrict__ adj, int n)
{
    __shared__ int cursor[RNG];
    const int b = blockIdx.x, tid = threadIdx.x;
    int nbase = b * RNG;
    for (int i = tid; i < RNG; i += 256) {
        int node = nbase + i;
        cursor[i] = (node < n) ? rowptr[node] : 0;
    }
    __syncthreads();
    int cnt = gcount[b];
    const unsigned int* buf = gbuf + (size_t)b * BCAP;
    for (int j = tid; j < cnt; j += 256) {
        unsigned int e = buf[j];
        int dl = e >> 17;
        int s = (int)(e & 0x1FFFFu);
        int pos = atomicAdd(&cursor[dl], 1);
        adj[pos] = s;
    }
}

// ---------------- Wcat = [Wmu | Wlv] ----------------
__global__ void k_build_wcat(const float* __restrict__ wmu, const float* __restrict__ wlv,
                             float* __restrict__ wcat) {
    int i = blockIdx.x * blockDim.x + threadIdx.x;  // 64*64
    if (i < 64 * 64) {
        int k = i >> 6, j = i & 63;
        wcat[i] = (j < 32) ? wmu[k * 32 + j] : wlv[k * 32 + (j - 32)];
    }
}

// ---------------- GEMM: U(bf16) = transform(A) @ W * dinv[row] ----------------
template <int K, bool TRANS>
__global__ __launch_bounds__(256) void k_gemm(
    const float* __restrict__ A, const float* __restrict__ W,
    const float* __restrict__ dinv, const float* __restrict__ alpha,
    const float* __restrict__ delta, unsigned short* __restrict__ U, int n)
{
    constexpr int SA = 68;                 // 64 + 4 pad
    __shared__ float As[64 * SA];
    __shared__ float Ws[K * 64];
    const int tid = threadIdx.x;
    const int brow = blockIdx.x * 64;
    const int tx = tid & 15, ty = tid >> 4;

    for (int i = tid; i < (K * 64) / 4; i += 256)
        reinterpret_cast<float4*>(Ws)[i] = reinterpret_cast<const float4*>(W)[i];

    float acc[4][4] = {};

    for (int kt = 0; kt < K; kt += 64) {
        __syncthreads();
        for (int i = tid; i < 64 * 16; i += 256) {
            int r = i >> 4, c4 = i & 15;
            int grow = brow + r;
            float4 v = {0.f, 0.f, 0.f, 0.f};
            if (grow < n) {
                v = reinterpret_cast<const float4*>(A)[(size_t)grow * (K / 4) + (kt >> 2) + c4];
                if (TRANS) {
                    float dv = dinv[grow];
                    int c = kt + c4 * 4;
                    v.x = fmaxf(fmaf(v.x * dv, alpha[c + 0], delta[c + 0]), 0.f);
                    v.y = fmaxf(fmaf(v.y * dv, alpha[c + 1], delta[c + 1]), 0.f);
                    v.z = fmaxf(fmaf(v.z * dv, alpha[c + 2], delta[c + 2]), 0.f);
                    v.w = fmaxf(fmaf(v.w * dv, alpha[c + 3], delta[c + 3]), 0.f);
                }
            }
            *reinterpret_cast<float4*>(&As[r * SA + c4 * 4]) = v;
        }
        __syncthreads();
#pragma unroll 8
        for (int k = 0; k < 64; ++k) {
            float4 b = *reinterpret_cast<const float4*>(&Ws[(kt + k) * 64 + tx * 4]);
#pragma unroll
            for (int i2 = 0; i2 < 4; ++i2) {
                float a = As[(ty * 4 + i2) * SA + k];
                acc[i2][0] = fmaf(a, b.x, acc[i2][0]);
                acc[i2][1] = fmaf(a, b.y, acc[i2][1]);
                acc[i2][2] = fmaf(a, b.z, acc[i2][2]);
                acc[i2][3] = fmaf(a, b.w, acc[i2][3]);
            }
        }
    }

#pragma unroll
    for (int i2 = 0; i2 < 4; ++i2) {
        int grow = brow + ty * 4 + i2;
        if (grow < n) {
            float dv = dinv[grow];
            ushort4 o;
            o.x = f2bf(acc[i2][0] * dv);
            o.y = f2bf(acc[i2][1] * dv);
            o.z = f2bf(acc[i2][2] * dv);
            o.w = f2bf(acc[i2][3] * dv);
            *reinterpret_cast<ushort4*>(&U[(size_t)grow * 64 + tx * 4]) = o;
        }
    }
}

// ---------------- gather core: 8-way unrolled, 8 independent accumulators ----------------
__device__ inline float gather_row(const int* __restrict__ rowptr, const int* __restrict__ adj,
                                   const unsigned short* __restrict__ u, int node, int lane)
{
    float acc = bf2f(u[(size_t)node * 64 + lane]);   // self-loop
    float a0 = 0.f, a1 = 0.f, a2 = 0.f, a3 = 0.f, a4 = 0.f, a5 = 0.f, a6 = 0.f, a7 = 0.f;
    int beg = rowptr[node], end = rowptr[node + 1];
    for (int cbeg = beg; cbeg < end; cbeg += 64) {
        int cnt = min(64, end - cbeg);
        int a = (lane < cnt) ? adj[cbeg + lane] : 0;
        int i = 0;
        for (; i + 8 <= cnt; i += 8) {
            int s0 = __shfl(a, i + 0), s1 = __shfl(a, i + 1);
            int s2 = __shfl(a, i + 2), s3 = __shfl(a, i + 3);
            int s4 = __shfl(a, i + 4), s5 = __shfl(a, i + 5);
            int s6 = __shfl(a, i + 6), s7 = __shfl(a, i + 7);
            float v0 = bf2f(u[(size_t)s0 * 64 + lane]);
            float v1 = bf2f(u[(size_t)s1 * 64 + lane]);
            float v2 = bf2f(u[(size_t)s2 * 64 + lane]);
            float v3 = bf2f(u[(size_t)s3 * 64 + lane]);
            float v4 = bf2f(u[(size_t)s4 * 64 + lane]);
            float v5 = bf2f(u[(size_t)s5 * 64 + lane]);
            float v6 = bf2f(u[(size_t)s6 * 64 + lane]);
            float v7 = bf2f(u[(size_t)s7 * 64 + lane]);
            a0 += v0; a1 += v1; a2 += v2; a3 += v3;
            a4 += v4; a5 += v5; a6 += v6; a7 += v7;
        }
        // remainder (deg mod 8), still 4-deep MLP typical
        for (; i < cnt; ++i) {
            int s = __shfl(a, i);
            a0 += bf2f(u[(size_t)s * 64 + lane]);
        }
    }
    return acc + ((a0 + a1) + (a2 + a3)) + ((a4 + a5) + (a6 + a7));
}

// ---------------- CSR aggregate: s[node] = u[node] + sum_{j in adj(node)} u[j] ----------------
__global__ __launch_bounds__(256) void k_aggregate(
    const int* __restrict__ rowptr, const int* __restrict__ adj,
    const unsigned short* __restrict__ u, float* __restrict__ s, int n)
{
    int wave = (blockIdx.x * blockDim.x + threadIdx.x) >> 6;
    int lane = threadIdx.x & 63;
    if (wave >= n) return;
    float acc = gather_row(rowptr, adj, u, wave, lane);
    s[(size_t)wave * 64 + lane] = acc;
}

// ---------------- CSR aggregate + final epilogue: out = [mu ; logvar] ----------------
__global__ __launch_bounds__(256) void k_aggregate_final(
    const int* __restrict__ rowptr, const int* __restrict__ adj,
    const unsigned short* __restrict__ u, const float* __restrict__ dinv,
    const float* __restrict__ bmu, const float* __restrict__ blv,
    float* __restrict__ out, int n)
{
    int wave = (blockIdx.x * blockDim.x + threadIdx.x) >> 6;
    int lane = threadIdx.x & 63;
    if (wave >= n) return;
    int node = wave;
    float acc = gather_row(rowptr, adj, u, node, lane);
    float dv = dinv[node];
    int total = n * 32;
    if (lane < 32)
        out[(size_t)node * 32 + lane] = fmaf(acc, dv, bmu[lane]);
    else
        out[(size_t)total + (size_t)node * 32 + (lane - 32)] = fmaf(acc, dv, blv[lane - 32]);
}

// ---------------- BN stats: sums/sumsq of y = s*dinv + b over rows ----------------
__global__ __launch_bounds__(256) void k_stats(
    const float* __restrict__ s, const float* __restrict__ dinv, const float* __restrict__ b,
    float* __restrict__ sums, float* __restrict__ sumsq, int n)
{
    __shared__ float red[2][256];
    int t = threadIdx.x;
    int c = t & 63, rg = t >> 6;   // 4 row-groups
    float bc = b[c];
    float ls = 0.f, lq = 0.f;
    for (int row = blockIdx.x * 4 + rg; row < n; row += gridDim.x * 4) {
        float y = fmaf(s[(size_t)row * 64 + c], dinv[row], bc);
        ls += y;
        lq = fmaf(y, y, lq);
    }
    red[0][t] = ls; red[1][t] = lq;
    __syncthreads();
    if (t < 64) {
        float a = red[0][t] + red[0][t + 64] + red[0][t + 128] + red[0][t + 192];
        float q = red[1][t] + red[1][t + 64] + red[1][t + 128] + red[1][t + 192];
        atomicAdd(&sums[t], a);
        atomicAdd(&sumsq[t], q);
    }
}

__global__ void k_bn_finalize(const float* __restrict__ sums, const float* __restrict__ sumsq,
                              const float* __restrict__ g, const float* __restrict__ be,
                              const float* __restrict__ b, float* __restrict__ alpha,
                              float* __restrict__ delta, int n)
{
    int c = threadIdx.x;  // 64
    float mu = sums[c] / (float)n;
    float var = sumsq[c] / (float)n - mu * mu;
    float inv = rsqrtf(var + 1e-5f);
    float a = inv * g[c];
    alpha[c] = a;
    delta[c] = fmaf(b[c] - mu, a, be[c]);
}

extern "C" void kernel_launch(void* const* d_in, const int* in_sizes, int n_in,
                              void* d_out, int out_size, void* d_ws, size_t ws_size,
                              hipStream_t stream) {
    const int N = NNODES, E = NEDGES;

    const float* x   = (const float*)d_in[0];
    const int* ei    = (const int*)d_in[1];
    const float* W1  = (const float*)d_in[2];
    const float* b1  = (const float*)d_in[3];
    const float* g1  = (const float*)d_in[4];
    const float* be1 = (const float*)d_in[5];
    const float* W2  = (const float*)d_in[6];
    const float* b2  = (const float*)d_in[7];
    const float* g2  = (const float*)d_in[8];
    const float* be2 = (const float*)d_in[9];
    const float* Wmu = (const float*)d_in[10];
    const float* bmu = (const float*)d_in[11];
    const float* Wlv = (const float*)d_in[12];
    const float* blv = (const float*)d_in[13];
    float* out = (float*)d_out;

    const int* src = ei;          // edge_index[0]
    const int* dst = ei + E;      // edge_index[1]

    // workspace layout (256B aligned chunks)
    char* ws = (char*)d_ws;
    size_t off = 0;
    auto alloc = [&](size_t bytes) { char* p = ws + off; off += (bytes + 255) & ~(size_t)255; return p; };
    float*          dinv   = (float*)alloc((size_t)N * 4);
    unsigned short* bufU   = (unsigned short*)alloc((size_t)N * 64 * 2);
    float*          bufS   = (float*)alloc((size_t)N * 64 * 4);
    int*            degi   = (int*)alloc((size_t)N * 4);
    int*            rowptr = (int*)alloc((size_t)(N + 1) * 4);
    int*            adj    = (int*)alloc((size_t)E * 4);
    unsigned int*   gbuf   = (unsigned int*)alloc((size_t)KBUCK * BCAP * 4);
    int*            gcount = (int*)alloc((size_t)KBUCK * 4);
    int*            partials = (int*)alloc(128 * 4);
    float*          Wcat   = (float*)alloc(64 * 64 * 4);
    float*          sums   = (float*)alloc(64 * 4);
    float*          sumsq  = (float*)alloc(64 * 4);
    float*          alpha  = (float*)alloc(64 * 4);
    float*          delta  = (float*)alloc(64 * 4);
    (void)ws_size;

    const int B = 256;
    dim3 blk(B);
    int gGemm  = (N + 63) / 64;          // 1563
    int gScan  = (N + 1023) / 1024;      // 98
    int gAgg   = (N + 3) / 4;            // 25000 (4 waves/block, 1 node/wave)
    int gBin   = (E + CHUNK - 1) / CHUNK; // 391

    // ---- build CSR: bin -> hist/dinv -> scan -> local fill ----
    hipMemsetAsync(gcount, 0, (size_t)KBUCK * 4, stream);
    k_bin<<<gBin, blk, 0, stream>>>(src, dst, gbuf, gcount, E);
    k_hist_dinv<<<KBUCK, blk, 0, stream>>>(gbuf, gcount, degi, dinv, N);
    k_block_reduce<<<gScan, blk, 0, stream>>>(degi, partials, N);
    k_scan_partials<<<1, 64, 0, stream>>>(partials, gScan);
    k_block_scan<<<gScan, blk, 0, stream>>>(degi, partials, rowptr, N, E);
    k_fill_local<<<KBUCK, blk, 0, stream>>>(gbuf, gcount, rowptr, adj, N);
    k_build_wcat<<<16, blk, 0, stream>>>(Wmu, Wlv, Wcat);

    // ---- layer 1 ----
    k_gemm<128, false><<<gGemm, blk, 0, stream>>>(x, W1, dinv, nullptr, nullptr, bufU, N);
    k_aggregate<<<gAgg, blk, 0, stream>>>(rowptr, adj, bufU, bufS, N);
    hipMemsetAsync(sums, 0, 512, stream);  // sums+sumsq contiguous (64*4=256 each)
    k_stats<<<256, blk, 0, stream>>>(bufS, dinv, b1, sums, sumsq, N);
    k_bn_finalize<<<1, 64, 0, stream>>>(sums, sumsq, g1, be1, b1, alpha, delta, N);

    // ---- layer 2 ----
    k_gemm<64, true><<<gGemm, blk, 0, stream>>>(bufS, W2, dinv, alpha, delta, bufU, N);
    k_aggregate<<<gAgg, blk, 0, stream>>>(rowptr, adj, bufU, bufS, N);
    hipMemsetAsync(sums, 0, 512, stream);
    k_stats<<<256, blk, 0, stream>>>(bufS, dinv, b2, sums, sumsq, N);
    k_bn_finalize<<<1, 64, 0, stream>>>(sums, sumsq, g2, be2, b2, alpha, delta, N);

    // ---- heads (mu ‖ logvar fused) + final epilogue ----
    k_gemm<64, true><<<gGemm, blk, 0, stream>>>(bufS, Wcat, dinv, alpha, delta, bufU, N);
    k_aggregate_final<<<gAgg, blk, 0, stream>>>(rowptr, adj, bufU, dinv, bmu, blv, out, N);
}